// Round 5
// baseline (320.520 us; speedup 1.0000x reference)
//
#include <hip/hip_runtime.h>
#include <hip/hip_cooperative_groups.h>
#include <stdint.h>

namespace cg = cooperative_groups;

// Problem constants (B=8, K=4, N=131072)
#define NTOT      4194304LL   // B*K*N
#define CHUNK     2048        // elements per block
#define NBLK      2048        // NTOT / CHUNK == 8 blocks/CU * 256 CU (full residency)
#define NEG_PAD   (-1000.0f)
#define NEG_IDLE  (-100000000.0f)
#define CAPS      768         // per-block dense-stage capacity (mean 614, +7.4 sigma)
#define CAPA      768

typedef unsigned long long u64;
typedef float float3u __attribute__((ext_vector_type(3), aligned(4)));   // dwordx3 fallback gather
typedef float float4a __attribute__((ext_vector_type(4), aligned(16)));
typedef int   int4v   __attribute__((ext_vector_type(4), aligned(16)));

// ===========================================================================
// FUSED cooperative kernel. Phase 1 == verified K1 body (minus cmp write:
// pack bits stay in LDS). grid.sync() == single-counter barrier, all 2048
// blocks resident (8/CU exactly). Phase 2 == verified R3 K2 body minus the
// cmp reload + rescan. All 2048 totals entries are written pre-sync every
// launch -> workspace poison can never be read.
// ===========================================================================
__global__ __launch_bounds__(256, 8) void fused_kernel(
    const float* __restrict__ rgb, const float* __restrict__ lsurf,
    const float* __restrict__ lair, const float* __restrict__ idle,
    const int* __restrict__ ms, const int* __restrict__ ma,
    u64* __restrict__ totals,
    unsigned rgb_max, unsigned ts_max, unsigned ta_max,
    float* __restrict__ out_rgb, float* __restrict__ out_ls, float* __restrict__ out_la)
{
    __shared__ unsigned wsum[4];
    __shared__ u64 wacc[4];
    __shared__ unsigned packLDS[256];     // u16 pack per 8 elements
    __shared__ unsigned prefLDS[256];     // packed exclusive local prefix (s | a<<16)
    __shared__ float4a rgbSrc4[(CAPS * 3 + 4 + 3) / 4];   // 9232 B raw window
    __shared__ float4a lsS4[(CAPS + 4 + 3) / 4];          // 3088 B
    __shared__ float4a laS4[(CAPA + 4 + 3) / 4];          // 3088 B
    float* const rgbSrc = (float*)rgbSrc4;
    float* const lsS    = (float*)lsS4;
    float* const laS    = (float*)laS4;

    const int t = threadIdx.x, lane = t & 63, wave = t >> 6;
    const unsigned bid = blockIdx.x;
    const long long base = (long long)bid * CHUNK;

    // ---------------- phase 1: masks -> pack bits + block totals ----------
    const int4v* ms4 = (const int4v*)(ms + base);
    const int4v* ma4 = (const int4v*)(ma + base);
    int4v s0 = __builtin_nontemporal_load(ms4 + 2 * t);
    int4v s1 = __builtin_nontemporal_load(ms4 + 2 * t + 1);
    int4v a0 = __builtin_nontemporal_load(ma4 + 2 * t);
    int4v a1 = __builtin_nontemporal_load(ma4 + 2 * t + 1);
    const float idle_v = idle[(int)(base >> 17)];     // chunk lies in one (b,k) row
    unsigned sbits = (unsigned)(s0[0] != 0)        | ((unsigned)(s0[1] != 0) << 1)
                   | ((unsigned)(s0[2] != 0) << 2) | ((unsigned)(s0[3] != 0) << 3)
                   | ((unsigned)(s1[0] != 0) << 4) | ((unsigned)(s1[1] != 0) << 5)
                   | ((unsigned)(s1[2] != 0) << 6) | ((unsigned)(s1[3] != 0) << 7);
    unsigned abits = (unsigned)(a0[0] != 0)        | ((unsigned)(a0[1] != 0) << 1)
                   | ((unsigned)(a0[2] != 0) << 2) | ((unsigned)(a0[3] != 0) << 3)
                   | ((unsigned)(a1[0] != 0) << 4) | ((unsigned)(a1[1] != 0) << 5)
                   | ((unsigned)(a1[2] != 0) << 6) | ((unsigned)(a1[3] != 0) << 7);
    unsigned pk = sbits | (abits << 8);
    packLDS[t] = pk;
    unsigned cnt = __popc(sbits) | (__popc(abits) << 16);

    unsigned x = cnt;                                 // wave-inclusive scan
    #pragma unroll
    for (int o = 1; o < 64; o <<= 1) {
        unsigned y = __shfl_up(x, o, 64);
        if (lane >= o) x += y;
    }
    if (lane == 63) wsum[wave] = x;
    __syncthreads();
    unsigned pre = (wave > 0 ? wsum[0] : 0u) + (wave > 1 ? wsum[1] : 0u)
                 + (wave > 2 ? wsum[2] : 0u);
    prefLDS[t] = pre + x - cnt;                       // per-pack exclusive (packed)
    unsigned totPk = wsum[0] + wsum[1] + wsum[2] + wsum[3];
    if (t == 0)
        totals[bid] = (u64)(totPk & 0xffffu) | ((u64)(totPk >> 16) << 32);

    // ---------------- grid-wide barrier (device-scope fence) --------------
    cg::this_grid().sync();

    // ---------------- phase 2: block base, staging, expand (== R3 K2) -----
    u64 acc = 0;
    #pragma unroll
    for (int j = 0; j < 8; ++j) {
        unsigned idx = (unsigned)t * 8u + (unsigned)j;
        acc += (idx < bid) ? totals[idx] : 0ULL;
    }
    #pragma unroll
    for (int o = 32; o; o >>= 1) acc += __shfl_down(acc, o, 64);
    if (lane == 0) wacc[wave] = acc;
    __syncthreads();
    u64 basesum = wacc[0] + wacc[1] + wacc[2] + wacc[3];
    const unsigned excS = (unsigned)(basesum & 0xffffffffULL);
    const unsigned excA = (unsigned)(basesum >> 32);
    const unsigned totS = totPk & 0xffffu;
    const unsigned totA = totPk >> 16;

    // dense source staging: float4 over aligned raw windows, read-once.
    const unsigned nS = totS < CAPS ? totS : CAPS;
    const unsigned nA = totA < CAPA ? totA : CAPA;
    const unsigned ofsR = (excS * 3u) & 3u;
    const unsigned ofsS = excS & 3u;
    const unsigned ofsA = excA & 3u;
    {
        const unsigned FR = ofsR + nS * 3u, nvR = FR >> 2, tlR = FR & 3u;
        const unsigned FS = ofsS + nS,      nvS = FS >> 2, tlS = FS & 3u;
        const unsigned FA = ofsA + nA,      nvA = FA >> 2, tlA = FA & 3u;
        const float4a* sR = (const float4a*)(rgb + (excS * 3u - ofsR));
        const float4a* sS = (const float4a*)(lsurf + (excS - ofsS));
        const float4a* sA = (const float4a*)(lair + (excA - ofsA));
        for (unsigned i = t; i < nvR; i += 256u)
            rgbSrc4[i] = __builtin_nontemporal_load(sR + i);
        for (unsigned i = t; i < nvS; i += 256u)
            lsS4[i] = __builtin_nontemporal_load(sS + i);
        for (unsigned i = t; i < nvA; i += 256u)
            laS4[i] = __builtin_nontemporal_load(sA + i);
        if ((unsigned)t < tlR) rgbSrc[4u * nvR + t] = rgb[excS * 3u - ofsR + 4u * nvR + t];
        if ((unsigned)t < tlS) lsS[4u * nvS + t]    = lsurf[excS - ofsS + 4u * nvS + t];
        if ((unsigned)t < tlA) laS[4u * nvA + t]    = lair[excA - ofsA + 4u * nvA + t];
    }
    __syncthreads();

    const float alive     = 1.0f - idle_v;
    const float idle_term = idle_v * NEG_IDLE;
    const int  sub = t >> 3, b = t & 7;
    const unsigned bm = (1u << b) - 1u;
    const int  hp = t >> 1;                // pack within half for ls/la ownership
    const unsigned nib = (unsigned)(t & 1) * 4u;
    const unsigned nm  = (1u << nib) - 1u;

    // rgb: 8 rounds of 256 elements; per-instruction-contiguous NT dword stores
    #pragma unroll
    for (int g = 0; g < 8; ++g) {
        const int p = (g << 5) + sub;
        unsigned w  = packLDS[p];
        unsigned pv = prefLDS[p];
        const long long e = base + g * 256 + t;
        float vx = 0.f, vy = 0.f, vz = 0.f;
        if ((w >> b) & 1u) {
            unsigned lr = (pv & 0xffffu) + __popc(w & bm);   // local rank
            if (lr < CAPS) {
                vx = rgbSrc[ofsR + 3u * lr];
                vy = rgbSrc[ofsR + 3u * lr + 1u];
                vz = rgbSrc[ofsR + 3u * lr + 2u];
            } else {                                // never-taken overflow path
                unsigned pr = excS + lr; pr = pr < rgb_max ? pr : rgb_max;
                float3u v = *(const float3u*)(rgb + 3LL * pr);
                vx = v.x; vy = v.y; vz = v.z;
            }
            vx *= alive; vy *= alive; vz *= alive;
        }
        __builtin_nontemporal_store(vx, out_rgb + 3 * e);
        __builtin_nontemporal_store(vy, out_rgb + 3 * e + 1);
        __builtin_nontemporal_store(vz, out_rgb + 3 * e + 2);
    }

    // ls/la: 4 consecutive elements per thread, LDS picks, NT float4
    #pragma unroll
    for (int h = 0; h < 2; ++h) {
        const int p = h * 128 + hp;
        unsigned w  = packLDS[p];
        unsigned pv = prefLDS[p];
        unsigned ws = w & 0xffu, wa = (w >> 8) & 0xffu;
        unsigned baseS = (pv & 0xffffu) + __popc(ws & nm);   // local rank of elem 0
        unsigned baseA = (pv >> 16)     + __popc(wa & nm);
        unsigned sb = (ws >> nib) & 0xFu;
        unsigned ab = (wa >> nib) & 0xFu;
        float lsv[4], lav[4];
        #pragma unroll
        for (int j = 0; j < 4; ++j) {
            unsigned mj = (1u << j) - 1u;
            unsigned rs = baseS + __popc(sb & mj);
            float vs = rs < CAPS ? lsS[ofsS + rs]
                     : lsurf[(excS + rs) < ts_max ? (excS + rs) : ts_max];
            lsv[j] = ((sb >> j) & 1u) ? vs * alive + idle_term : NEG_PAD;
            unsigned ra = baseA + __popc(ab & mj);
            float va = ra < CAPA ? laS[ofsA + ra]
                     : lair[(excA + ra) < ta_max ? (excA + ra) : ta_max];
            lav[j] = ((ab >> j) & 1u) ? va * alive + idle_term : NEG_PAD;
        }
        const long long eb = base + h * 1024 + 4 * t;  // 16-B aligned
        float4a vls; vls.x = lsv[0]; vls.y = lsv[1]; vls.z = lsv[2]; vls.w = lsv[3];
        float4a vla; vla.x = lav[0]; vla.y = lav[1]; vla.z = lav[2]; vla.w = lav[3];
        __builtin_nontemporal_store(vls, (float4a*)(out_ls + eb));
        __builtin_nontemporal_store(vla, (float4a*)(out_la + eb));
    }
}

// ===========================================================================
// Fallback path: the verified R3 two-kernel pair, byte-identical. Used only
// if cooperative launch is unavailable or fails.
// ===========================================================================
__global__ __launch_bounds__(256, 8) void count_kernel(
    const int* __restrict__ ms, const int* __restrict__ ma,
    unsigned short* __restrict__ cmp, u64* __restrict__ totals)
{
    const int t = threadIdx.x, lane = t & 63, wave = t >> 6;
    const unsigned bid = blockIdx.x;
    const long long base = (long long)bid * CHUNK;

    const int4v* ms4 = (const int4v*)(ms + base);
    const int4v* ma4 = (const int4v*)(ma + base);
    int4v s0 = __builtin_nontemporal_load(ms4 + 2 * t);
    int4v s1 = __builtin_nontemporal_load(ms4 + 2 * t + 1);
    int4v a0 = __builtin_nontemporal_load(ma4 + 2 * t);
    int4v a1 = __builtin_nontemporal_load(ma4 + 2 * t + 1);
    unsigned sbits = (unsigned)(s0[0] != 0)        | ((unsigned)(s0[1] != 0) << 1)
                   | ((unsigned)(s0[2] != 0) << 2) | ((unsigned)(s0[3] != 0) << 3)
                   | ((unsigned)(s1[0] != 0) << 4) | ((unsigned)(s1[1] != 0) << 5)
                   | ((unsigned)(s1[2] != 0) << 6) | ((unsigned)(s1[3] != 0) << 7);
    unsigned abits = (unsigned)(a0[0] != 0)        | ((unsigned)(a0[1] != 0) << 1)
                   | ((unsigned)(a0[2] != 0) << 2) | ((unsigned)(a0[3] != 0) << 3)
                   | ((unsigned)(a1[0] != 0) << 4) | ((unsigned)(a1[1] != 0) << 5)
                   | ((unsigned)(a1[2] != 0) << 6) | ((unsigned)(a1[3] != 0) << 7);

    cmp[bid * 256u + (unsigned)t] = (unsigned short)(sbits | (abits << 8));

    unsigned cnt = __popc(sbits) | (__popc(abits) << 16);
    #pragma unroll
    for (int o = 32; o; o >>= 1) cnt += __shfl_down(cnt, o, 64);
    __shared__ unsigned lds[4];
    if (lane == 0) lds[wave] = cnt;
    __syncthreads();
    if (t == 0) {
        unsigned tot = lds[0] + lds[1] + lds[2] + lds[3];
        totals[bid] = (u64)(tot & 0xffffu) | ((u64)(tot >> 16) << 32);
    }
}

__global__ __launch_bounds__(256, 8) void expand_kernel(
    const float* __restrict__ rgb, const float* __restrict__ lsurf,
    const float* __restrict__ lair, const float* __restrict__ idle,
    const unsigned short* __restrict__ cmp, const u64* __restrict__ totals,
    unsigned rgb_max, unsigned ts_max, unsigned ta_max,
    float* __restrict__ out_rgb, float* __restrict__ out_ls, float* __restrict__ out_la)
{
    __shared__ unsigned wsum[4];
    __shared__ u64 wacc[4];
    __shared__ unsigned packLDS[256];
    __shared__ unsigned prefLDS[256];
    __shared__ float4a rgbSrc4[(CAPS * 3 + 4 + 3) / 4];
    __shared__ float4a lsS4[(CAPS + 4 + 3) / 4];
    __shared__ float4a laS4[(CAPA + 4 + 3) / 4];
    float* const rgbSrc = (float*)rgbSrc4;
    float* const lsS    = (float*)lsS4;
    float* const laS    = (float*)laS4;

    const int t = threadIdx.x, lane = t & 63, wave = t >> 6;
    const unsigned bid = blockIdx.x;
    const long long base = (long long)bid * CHUNK;

    unsigned pk = cmp[bid * 256u + (unsigned)t];
    u64 acc = 0;
    #pragma unroll
    for (int j = 0; j < 8; ++j) {
        unsigned idx = (unsigned)t * 8u + (unsigned)j;
        acc += (idx < bid) ? totals[idx] : 0ULL;
    }
    const float idle_v = idle[(int)(base >> 17)];

    packLDS[t] = pk;
    unsigned cnt = __popc(pk & 0xffu) | (__popc(pk >> 8) << 16);

    unsigned x = cnt;
    #pragma unroll
    for (int o = 1; o < 64; o <<= 1) {
        unsigned y = __shfl_up(x, o, 64);
        if (lane >= o) x += y;
    }
    if (lane == 63) wsum[wave] = x;
    #pragma unroll
    for (int o = 32; o; o >>= 1) acc += __shfl_down(acc, o, 64);
    if (lane == 0) wacc[wave] = acc;
    __syncthreads();
    unsigned pre = (wave > 0 ? wsum[0] : 0u) + (wave > 1 ? wsum[1] : 0u)
                 + (wave > 2 ? wsum[2] : 0u);
    prefLDS[t] = pre + x - cnt;
    u64 basesum = wacc[0] + wacc[1] + wacc[2] + wacc[3];
    const unsigned excS = (unsigned)(basesum & 0xffffffffULL);
    const unsigned excA = (unsigned)(basesum >> 32);
    unsigned totPk = wsum[0] + wsum[1] + wsum[2] + wsum[3];
    const unsigned totS = totPk & 0xffffu;
    const unsigned totA = totPk >> 16;

    const unsigned nS = totS < CAPS ? totS : CAPS;
    const unsigned nA = totA < CAPA ? totA : CAPA;
    const unsigned ofsR = (excS * 3u) & 3u;
    const unsigned ofsS = excS & 3u;
    const unsigned ofsA = excA & 3u;
    {
        const unsigned FR = ofsR + nS * 3u, nvR = FR >> 2, tlR = FR & 3u;
        const unsigned FS = ofsS + nS,      nvS = FS >> 2, tlS = FS & 3u;
        const unsigned FA = ofsA + nA,      nvA = FA >> 2, tlA = FA & 3u;
        const float4a* sR = (const float4a*)(rgb + (excS * 3u - ofsR));
        const float4a* sS = (const float4a*)(lsurf + (excS - ofsS));
        const float4a* sA = (const float4a*)(lair + (excA - ofsA));
        for (unsigned i = t; i < nvR; i += 256u)
            rgbSrc4[i] = __builtin_nontemporal_load(sR + i);
        for (unsigned i = t; i < nvS; i += 256u)
            lsS4[i] = __builtin_nontemporal_load(sS + i);
        for (unsigned i = t; i < nvA; i += 256u)
            laS4[i] = __builtin_nontemporal_load(sA + i);
        if ((unsigned)t < tlR) rgbSrc[4u * nvR + t] = rgb[excS * 3u - ofsR + 4u * nvR + t];
        if ((unsigned)t < tlS) lsS[4u * nvS + t]    = lsurf[excS - ofsS + 4u * nvS + t];
        if ((unsigned)t < tlA) laS[4u * nvA + t]    = lair[excA - ofsA + 4u * nvA + t];
    }
    __syncthreads();

    const float alive     = 1.0f - idle_v;
    const float idle_term = idle_v * NEG_IDLE;
    const int  sub = t >> 3, b = t & 7;
    const unsigned bm = (1u << b) - 1u;
    const int  hp = t >> 1;
    const unsigned nib = (unsigned)(t & 1) * 4u;
    const unsigned nm  = (1u << nib) - 1u;

    #pragma unroll
    for (int g = 0; g < 8; ++g) {
        const int p = (g << 5) + sub;
        unsigned w  = packLDS[p];
        unsigned pv = prefLDS[p];
        const long long e = base + g * 256 + t;
        float vx = 0.f, vy = 0.f, vz = 0.f;
        if ((w >> b) & 1u) {
            unsigned lr = (pv & 0xffffu) + __popc(w & bm);
            if (lr < CAPS) {
                vx = rgbSrc[ofsR + 3u * lr];
                vy = rgbSrc[ofsR + 3u * lr + 1u];
                vz = rgbSrc[ofsR + 3u * lr + 2u];
            } else {
                unsigned pr = excS + lr; pr = pr < rgb_max ? pr : rgb_max;
                float3u v = *(const float3u*)(rgb + 3LL * pr);
                vx = v.x; vy = v.y; vz = v.z;
            }
            vx *= alive; vy *= alive; vz *= alive;
        }
        __builtin_nontemporal_store(vx, out_rgb + 3 * e);
        __builtin_nontemporal_store(vy, out_rgb + 3 * e + 1);
        __builtin_nontemporal_store(vz, out_rgb + 3 * e + 2);
    }

    #pragma unroll
    for (int h = 0; h < 2; ++h) {
        const int p = h * 128 + hp;
        unsigned w  = packLDS[p];
        unsigned pv = prefLDS[p];
        unsigned ws = w & 0xffu, wa = (w >> 8) & 0xffu;
        unsigned baseS = (pv & 0xffffu) + __popc(ws & nm);
        unsigned baseA = (pv >> 16)     + __popc(wa & nm);
        unsigned sb = (ws >> nib) & 0xFu;
        unsigned ab = (wa >> nib) & 0xFu;
        float lsv[4], lav[4];
        #pragma unroll
        for (int j = 0; j < 4; ++j) {
            unsigned mj = (1u << j) - 1u;
            unsigned rs = baseS + __popc(sb & mj);
            float vs = rs < CAPS ? lsS[ofsS + rs]
                     : lsurf[(excS + rs) < ts_max ? (excS + rs) : ts_max];
            lsv[j] = ((sb >> j) & 1u) ? vs * alive + idle_term : NEG_PAD;
            unsigned ra = baseA + __popc(ab & mj);
            float va = ra < CAPA ? laS[ofsA + ra]
                     : lair[(excA + ra) < ta_max ? (excA + ra) : ta_max];
            lav[j] = ((ab >> j) & 1u) ? va * alive + idle_term : NEG_PAD;
        }
        const long long eb = base + h * 1024 + 4 * t;
        float4a vls; vls.x = lsv[0]; vls.y = lsv[1]; vls.z = lsv[2]; vls.w = lsv[3];
        float4a vla; vla.x = lav[0]; vla.y = lav[1]; vla.z = lav[2]; vla.w = lav[3];
        __builtin_nontemporal_store(vls, (float4a*)(out_ls + eb));
        __builtin_nontemporal_store(vla, (float4a*)(out_la + eb));
    }
}

extern "C" void kernel_launch(void* const* d_in, const int* in_sizes, int n_in,
                              void* d_out, int out_size, void* d_ws, size_t ws_size,
                              hipStream_t stream)
{
    const float* rgb   = (const float*)d_in[0];
    const float* lsurf = (const float*)d_in[1];
    const float* lair  = (const float*)d_in[2];
    const float* idle  = (const float*)d_in[3];
    const int*   ms    = (const int*)d_in[4];   // bool -> int32 per harness contract
    const int*   ma    = (const int*)d_in[5];

    unsigned rgb_max = (unsigned)(in_sizes[0] / 3 - 1);
    unsigned ts_max  = (unsigned)(in_sizes[1] - 1);
    unsigned ta_max  = (unsigned)(in_sizes[2] - 1);

    float* out     = (float*)d_out;
    float* out_rgb = out;                  // (B,K,N,3)
    float* out_ls  = out + NTOT * 3;       // (B,K,N,1)
    float* out_la  = out_ls + NTOT;        // (B,K,N,1)

    // Workspace: totals (16 KB) then, for the fallback path only, cmp (1 MB).
    // All totals entries rewritten pre-sync every launch -> poison-safe.
    u64* totals = (u64*)d_ws;
    unsigned short* cmp = (unsigned short*)((char*)d_ws + 16384);

    static int coop_ok = -1;
    if (coop_ok < 0) {                      // host-side query, not a stream op
        int dev = 0, v = 0;
        (void)hipGetDevice(&dev);
        if (hipDeviceGetAttribute(&v, hipDeviceAttributeCooperativeLaunch, dev)
            != hipSuccess) v = 0;
        coop_ok = v;
    }

    hipError_t err = hipErrorUnknown;
    if (coop_ok) {
        void* args[] = {
            (void*)&rgb, (void*)&lsurf, (void*)&lair, (void*)&idle,
            (void*)&ms, (void*)&ma, (void*)&totals,
            (void*)&rgb_max, (void*)&ts_max, (void*)&ta_max,
            (void*)&out_rgb, (void*)&out_ls, (void*)&out_la
        };
        err = hipLaunchCooperativeKernel((const void*)fused_kernel,
                                         dim3(NBLK), dim3(256), args, 0, stream);
    }
    if (err != hipSuccess) {                // verified R3 two-kernel fallback
        count_kernel<<<NBLK, 256, 0, stream>>>(ms, ma, cmp, totals);
        expand_kernel<<<NBLK, 256, 0, stream>>>(rgb, lsurf, lair, idle, cmp, totals,
                                                rgb_max, ts_max, ta_max,
                                                out_rgb, out_ls, out_la);
    }
}

// Round 6
// 140.704 us; speedup vs baseline: 2.2780x; 2.2780x over previous
//
#include <hip/hip_runtime.h>
#include <stdint.h>

// Problem constants (B=8, K=4, N=131072)
#define NTOT      4194304LL   // B*K*N
#define CHUNK     2048        // elements per block
#define NBLK      2048        // NTOT / CHUNK
#define NEG_PAD   (-1000.0f)
#define NEG_IDLE  (-100000000.0f)
#define CAPS      768         // per-block dense-stage capacity (mean 614, +7.4 sigma)
#define CAPA      768

typedef unsigned long long u64;
typedef float float3u __attribute__((ext_vector_type(3), aligned(4)));   // dwordx3 fallback gather
typedef float float4a __attribute__((ext_vector_type(4), aligned(16)));
typedef int   int4v   __attribute__((ext_vector_type(4), aligned(16)));

// ---------------------------------------------------------------------------
// K1: read masks ONCE (nontemporal int4); emit per-8-element compressed
// bitmasks (u16: sbits | abits<<8) and per-block packed totals (s | a<<32).
// At its HBM floor (~5.5 us): 33.6 MB read + 1 MB write. Verified R3 body.
// ---------------------------------------------------------------------------
__global__ __launch_bounds__(256, 8) void count_kernel(
    const int* __restrict__ ms, const int* __restrict__ ma,
    unsigned short* __restrict__ cmp, u64* __restrict__ totals)
{
    const int t = threadIdx.x, lane = t & 63, wave = t >> 6;
    const unsigned bid = blockIdx.x;
    const long long base = (long long)bid * CHUNK;

    const int4v* ms4 = (const int4v*)(ms + base);
    const int4v* ma4 = (const int4v*)(ma + base);
    int4v s0 = __builtin_nontemporal_load(ms4 + 2 * t);
    int4v s1 = __builtin_nontemporal_load(ms4 + 2 * t + 1);
    int4v a0 = __builtin_nontemporal_load(ma4 + 2 * t);
    int4v a1 = __builtin_nontemporal_load(ma4 + 2 * t + 1);
    unsigned sbits = (unsigned)(s0[0] != 0)        | ((unsigned)(s0[1] != 0) << 1)
                   | ((unsigned)(s0[2] != 0) << 2) | ((unsigned)(s0[3] != 0) << 3)
                   | ((unsigned)(s1[0] != 0) << 4) | ((unsigned)(s1[1] != 0) << 5)
                   | ((unsigned)(s1[2] != 0) << 6) | ((unsigned)(s1[3] != 0) << 7);
    unsigned abits = (unsigned)(a0[0] != 0)        | ((unsigned)(a0[1] != 0) << 1)
                   | ((unsigned)(a0[2] != 0) << 2) | ((unsigned)(a0[3] != 0) << 3)
                   | ((unsigned)(a1[0] != 0) << 4) | ((unsigned)(a1[1] != 0) << 5)
                   | ((unsigned)(a1[2] != 0) << 6) | ((unsigned)(a1[3] != 0) << 7);

    cmp[bid * 256u + (unsigned)t] = (unsigned short)(sbits | (abits << 8));

    unsigned cnt = __popc(sbits) | (__popc(abits) << 16);
    #pragma unroll
    for (int o = 32; o; o >>= 1) cnt += __shfl_down(cnt, o, 64);
    __shared__ unsigned lds[4];
    if (lane == 0) lds[wave] = cnt;
    __syncthreads();
    if (t == 0) {
        unsigned tot = lds[0] + lds[1] + lds[2] + lds[3];
        totals[bid] = (u64)(tot & 0xffffu) | ((u64)(tot >> 16) << 32);
    }
}

// ---------------------------------------------------------------------------
// K2: block base via predicated sum of the 16 KB totals array (L3-hot);
// per-pack prefixes via one block scan; dense source slices staged into LDS
// with float4 loads (aligned raw windows, exact bounds). Outputs all
// nontemporal; rgb stored directly as 3 NT dword stores/thread (each wave
// instruction covers a contiguous 768 B span -> L2 write-combines to full
// lines). LDS 17.5 KB -> 8 blocks/CU = full residency for the 2048-block
// grid. Per-element global fallback covers the (never-taken) CAPS overflow.
// Verified R3 body (140.8 us total; prediction-matched).
// ---------------------------------------------------------------------------
__global__ __launch_bounds__(256, 8) void expand_kernel(
    const float* __restrict__ rgb, const float* __restrict__ lsurf,
    const float* __restrict__ lair, const float* __restrict__ idle,
    const unsigned short* __restrict__ cmp, const u64* __restrict__ totals,
    unsigned rgb_max, unsigned ts_max, unsigned ta_max,
    float* __restrict__ out_rgb, float* __restrict__ out_ls, float* __restrict__ out_la)
{
    __shared__ unsigned wsum[4];
    __shared__ u64 wacc[4];
    __shared__ unsigned packLDS[256];     // u16 pack per 8 elements
    __shared__ unsigned prefLDS[256];     // packed exclusive local prefix (s | a<<16)
    __shared__ float4a rgbSrc4[(CAPS * 3 + 4 + 3) / 4];   // 9232 B raw window
    __shared__ float4a lsS4[(CAPS + 4 + 3) / 4];          // 3088 B
    __shared__ float4a laS4[(CAPA + 4 + 3) / 4];          // 3088 B
    float* const rgbSrc = (float*)rgbSrc4;
    float* const lsS    = (float*)lsS4;
    float* const laS    = (float*)laS4;

    const int t = threadIdx.x, lane = t & 63, wave = t >> 6;
    const unsigned bid = blockIdx.x;
    const long long base = (long long)bid * CHUNK;

    // --- independent loads first ---
    unsigned pk = cmp[bid * 256u + (unsigned)t];
    u64 acc = 0;
    #pragma unroll
    for (int j = 0; j < 8; ++j) {
        unsigned idx = (unsigned)t * 8u + (unsigned)j;
        acc += (idx < bid) ? totals[idx] : 0ULL;
    }
    const float idle_v = idle[(int)(base >> 17)];     // chunk lies in one (b,k) row

    packLDS[t] = pk;
    unsigned cnt = __popc(pk & 0xffu) | (__popc(pk >> 8) << 16);

    unsigned x = cnt;                                 // wave-inclusive scan
    #pragma unroll
    for (int o = 1; o < 64; o <<= 1) {
        unsigned y = __shfl_up(x, o, 64);
        if (lane >= o) x += y;
    }
    if (lane == 63) wsum[wave] = x;
    #pragma unroll
    for (int o = 32; o; o >>= 1) acc += __shfl_down(acc, o, 64);
    if (lane == 0) wacc[wave] = acc;
    __syncthreads();
    unsigned pre = (wave > 0 ? wsum[0] : 0u) + (wave > 1 ? wsum[1] : 0u)
                 + (wave > 2 ? wsum[2] : 0u);
    prefLDS[t] = pre + x - cnt;                       // per-pack exclusive (packed)
    u64 basesum = wacc[0] + wacc[1] + wacc[2] + wacc[3];
    const unsigned excS = (unsigned)(basesum & 0xffffffffULL);
    const unsigned excA = (unsigned)(basesum >> 32);
    unsigned totPk = wsum[0] + wsum[1] + wsum[2] + wsum[3];
    const unsigned totS = totPk & 0xffffu;
    const unsigned totA = totPk >> 16;

    // ---- dense source staging: float4 over aligned raw windows, read-once.
    // Window [ab, ab+F): ab = 16B-aligned start, ofs = element offset inside.
    // All accesses stay within [slice_start_rounded_down, slice_end).
    const unsigned nS = totS < CAPS ? totS : CAPS;
    const unsigned nA = totA < CAPA ? totA : CAPA;
    const unsigned ofsR = (excS * 3u) & 3u;
    const unsigned ofsS = excS & 3u;
    const unsigned ofsA = excA & 3u;
    {
        const unsigned FR = ofsR + nS * 3u, nvR = FR >> 2, tlR = FR & 3u;
        const unsigned FS = ofsS + nS,      nvS = FS >> 2, tlS = FS & 3u;
        const unsigned FA = ofsA + nA,      nvA = FA >> 2, tlA = FA & 3u;
        const float4a* sR = (const float4a*)(rgb + (excS * 3u - ofsR));
        const float4a* sS = (const float4a*)(lsurf + (excS - ofsS));
        const float4a* sA = (const float4a*)(lair + (excA - ofsA));
        for (unsigned i = t; i < nvR; i += 256u)
            rgbSrc4[i] = __builtin_nontemporal_load(sR + i);
        for (unsigned i = t; i < nvS; i += 256u)
            lsS4[i] = __builtin_nontemporal_load(sS + i);
        for (unsigned i = t; i < nvA; i += 256u)
            laS4[i] = __builtin_nontemporal_load(sA + i);
        if ((unsigned)t < tlR) rgbSrc[4u * nvR + t] = rgb[excS * 3u - ofsR + 4u * nvR + t];
        if ((unsigned)t < tlS) lsS[4u * nvS + t]    = lsurf[excS - ofsS + 4u * nvS + t];
        if ((unsigned)t < tlA) laS[4u * nvA + t]    = lair[excA - ofsA + 4u * nvA + t];
    }
    __syncthreads();

    const float alive     = 1.0f - idle_v;
    const float idle_term = idle_v * NEG_IDLE;
    const int  sub = t >> 3, b = t & 7;
    const unsigned bm = (1u << b) - 1u;
    const int  hp = t >> 1;                // pack within half for ls/la ownership
    const unsigned nib = (unsigned)(t & 1) * 4u;
    const unsigned nm  = (1u << nib) - 1u;

    // ---- rgb: 8 rounds of 256 elements; element = g*256 + t; direct NT stores
    #pragma unroll
    for (int g = 0; g < 8; ++g) {
        const int p = (g << 5) + sub;
        unsigned w  = packLDS[p];
        unsigned pv = prefLDS[p];
        const long long e = base + g * 256 + t;
        float vx = 0.f, vy = 0.f, vz = 0.f;
        if ((w >> b) & 1u) {
            unsigned lr = (pv & 0xffffu) + __popc(w & bm);   // local rank
            if (lr < CAPS) {
                vx = rgbSrc[ofsR + 3u * lr];
                vy = rgbSrc[ofsR + 3u * lr + 1u];
                vz = rgbSrc[ofsR + 3u * lr + 2u];
            } else {                                // never-taken overflow path
                unsigned pr = excS + lr; pr = pr < rgb_max ? pr : rgb_max;
                float3u v = *(const float3u*)(rgb + 3LL * pr);
                vx = v.x; vy = v.y; vz = v.z;
            }
            vx *= alive; vy *= alive; vz *= alive;
        }
        __builtin_nontemporal_store(vx, out_rgb + 3 * e);
        __builtin_nontemporal_store(vy, out_rgb + 3 * e + 1);
        __builtin_nontemporal_store(vz, out_rgb + 3 * e + 2);
    }

    // ---- ls/la: 4 consecutive elements per thread, LDS picks, NT float4 ----
    #pragma unroll
    for (int h = 0; h < 2; ++h) {
        const int p = h * 128 + hp;
        unsigned w  = packLDS[p];
        unsigned pv = prefLDS[p];
        unsigned ws = w & 0xffu, wa = (w >> 8) & 0xffu;
        unsigned baseS = (pv & 0xffffu) + __popc(ws & nm);   // local rank of elem 0
        unsigned baseA = (pv >> 16)     + __popc(wa & nm);
        unsigned sb = (ws >> nib) & 0xFu;
        unsigned ab = (wa >> nib) & 0xFu;
        float lsv[4], lav[4];
        #pragma unroll
        for (int j = 0; j < 4; ++j) {
            unsigned mj = (1u << j) - 1u;
            unsigned rs = baseS + __popc(sb & mj);
            float vs = rs < CAPS ? lsS[ofsS + rs]
                     : lsurf[(excS + rs) < ts_max ? (excS + rs) : ts_max];
            lsv[j] = ((sb >> j) & 1u) ? vs * alive + idle_term : NEG_PAD;
            unsigned ra = baseA + __popc(ab & mj);
            float va = ra < CAPA ? laS[ofsA + ra]
                     : lair[(excA + ra) < ta_max ? (excA + ra) : ta_max];
            lav[j] = ((ab >> j) & 1u) ? va * alive + idle_term : NEG_PAD;
        }
        const long long eb = base + h * 1024 + 4 * t;  // 16-B aligned
        float4a vls; vls.x = lsv[0]; vls.y = lsv[1]; vls.z = lsv[2]; vls.w = lsv[3];
        float4a vla; vla.x = lav[0]; vla.y = lav[1]; vla.z = lav[2]; vla.w = lav[3];
        __builtin_nontemporal_store(vls, (float4a*)(out_ls + eb));
        __builtin_nontemporal_store(vla, (float4a*)(out_la + eb));
    }
}

extern "C" void kernel_launch(void* const* d_in, const int* in_sizes, int n_in,
                              void* d_out, int out_size, void* d_ws, size_t ws_size,
                              hipStream_t stream)
{
    const float* rgb   = (const float*)d_in[0];
    const float* lsurf = (const float*)d_in[1];
    const float* lair  = (const float*)d_in[2];
    const float* idle  = (const float*)d_in[3];
    const int*   ms    = (const int*)d_in[4];   // bool -> int32 per harness contract
    const int*   ma    = (const int*)d_in[5];

    unsigned rgb_max = (unsigned)(in_sizes[0] / 3 - 1);
    unsigned ts_max  = (unsigned)(in_sizes[1] - 1);
    unsigned ta_max  = (unsigned)(in_sizes[2] - 1);

    float* out     = (float*)d_out;
    float* out_rgb = out;                  // (B,K,N,3)
    float* out_ls  = out + NTOT * 3;       // (B,K,N,1)
    float* out_la  = out_ls + NTOT;        // (B,K,N,1)

    // Workspace: totals (16 KB) then compressed masks (1 MB); both fully
    // rewritten by K1 every launch -> no init needed despite 0xAA poison.
    u64* totals = (u64*)d_ws;
    unsigned short* cmp = (unsigned short*)((char*)d_ws + 16384);

    count_kernel<<<NBLK, 256, 0, stream>>>(ms, ma, cmp, totals);
    expand_kernel<<<NBLK, 256, 0, stream>>>(rgb, lsurf, lair, idle, cmp, totals,
                                            rgb_max, ts_max, ta_max,
                                            out_rgb, out_ls, out_la);
}